// Round 6
// baseline (984.648 us; speedup 1.0000x reference)
//
#include <hip/hip_runtime.h>

typedef float f32x4 __attribute__((ext_vector_type(4)));

#define NXg   512
#define NYg   512
#define NTt   400
#define DIMg  520
#define DTc   0.001f
#define Hc    10.0f
#define KSTEP 4
#define NCHUNK 100

#define TILE_W 64          // x extent of staged tile (own 32 + 2*16 halo)
#define TILE_H 40          // y extent of staged tile (own 8 + 2*16 halo)
#define TSTR   68          // padded LDS row stride (floats)
#define NQROW  16          // f32x4 quads per tile row
#define NQUADS (TILE_H * NQROW)   // 640

#define C0f (-205.0f/72.0f)
#define C1f (8.0f/5.0f)
#define C2f (-1.0f/5.0f)
#define C3f (8.0f/315.0f)
#define C4f (-1.0f/560.0f)

// One-time per call: scale[] (mask folded in: 0 on pad ring), zero fields,
// params: ints [0..2]=srcY,srcX,recY ; floats [4+t]=w[t]*amp.
__global__ void time2d_init(const float* __restrict__ vel,
                            const float* __restrict__ w,
                            const int* __restrict__ sxp,
                            const int* __restrict__ syp,
                            const int* __restrict__ ryp,
                            float* __restrict__ scale,
                            float* __restrict__ fields,
                            float* __restrict__ params) {
    int idx = blockIdx.x * blockDim.x + threadIdx.x;
    if (idx < DIMg * DIMg) {
        int y = idx / DIMg;
        int x = idx - y * DIMg;
        float s = 0.0f;
        if (y >= 4 && y < 516 && x >= 4 && x < 516) {
            // scale[y][x] = (vel[x-4][y-4]*DT)^2 / H^2   (transposed pad)
            float v = vel[(x - 4) * NYg + (y - 4)] * DTc;
            s = v * v / (Hc * Hc);
        }
        scale[idx] = s;
    }
    for (int i = idx; i < 4 * DIMg * DIMg; i += gridDim.x * blockDim.x)
        fields[i] = 0.0f;
    if (idx < NTt) {
        const int sx = *sxp, sy = *syp;
        const float va = vel[sx * NYg + sy] * DTc;
        params[4 + idx] = w[idx] * (va * va);
    }
    if (idx == 0) {
        int* pi = (int*)params;
        pi[0] = *syp + 4;   // srcY
        pi[1] = *sxp + 4;   // srcX
        pi[2] = *ryp + 4;   // recY
    }
}

// One chunk = K=4 steps. 1024 blocks (16x64) = 4 blocks/CU, 256 threads each
// (4 full waves, ALL active in compute) = 16 waves/CU. Block owns a 32x8
// interior tile, stages 64x40 into double-buffered LDS, runs 4 substeps with
// implicit erosion (fixed compute region [4,36); validity shrinks to the
// owned region exactly), writes back the owned region of the last two time
// levels. Blocks independent within a launch.
template<int K>
__launch_bounds__(256, 4)
__global__ void time2d_chunk(const float* __restrict__ Ps,
                             const float* __restrict__ Cs,
                             float* __restrict__ Pd,
                             float* __restrict__ Cd,
                             const float* __restrict__ scale,
                             const float* __restrict__ params,
                             float* __restrict__ out,
                             int t0)
{
    const int tid = threadIdx.x;
    const int bx = blockIdx.x, by = blockIdx.y;
    const int lx0 = bx * 32 - 12, ly0 = by * 8 - 12;   // tile origin (global)

    const int* pi = (const int*)params;
    const int srcY = pi[0], srcX = pi[1], recY = pi[2];

    __shared__ float lds[2][TILE_H * TSTR];

    // Stage cur tile (64x40) into LDS[0]; OOB -> 0 (pad semantics).
    #pragma unroll
    for (int ii = 0; ii < 3; ++ii) {
        const int pos = tid + 256 * ii;
        if (pos < NQUADS) {
            const int ty = pos >> 4, txq = pos & 15;
            const int gy = ly0 + ty, gx = lx0 + txq * 4;
            f32x4 v = (f32x4)0.0f;
            if ((unsigned)gy < 520u && (unsigned)gx < 517u)
                v = *(const f32x4*)&Cs[gy * DIMg + gx];
            *(f32x4*)&lds[0][ty * TSTR + txq * 4] = v;
        }
    }

    // Compute mapping: 1 quad wide x 2 rows per thread, rows [4,36) x 16 qcols.
    const int xc = tid & 15, pr = tid >> 4;   // pr 0..15
    const int x4 = xc * 4;
    const int rb = 4 + pr * 2;                // computed rows rb, rb+1
    const int gx0 = lx0 + x4;
    const bool ownedCol = (xc >= 4 && xc < 12);   // own local x [16,48)

    f32x4 scq[2], prevq[2], valq[2];
    int srcI = -1, srcJ = 0;
    bool rec[2], ownRow[2];
    int gyv[2];
    #pragma unroll
    for (int i = 0; i < 2; ++i) {
        const int gy = ly0 + rb + i;
        gyv[i] = gy;
        f32x4 s = (f32x4)0.0f, pv = (f32x4)0.0f;
        if ((unsigned)gy < 520u && (unsigned)gx0 < 517u) {
            s  = *(const f32x4*)&scale[gy * DIMg + gx0];
            pv = *(const f32x4*)&Ps[gy * DIMg + gx0];
        }
        scq[i] = s; prevq[i] = pv;
        #pragma unroll
        for (int j = 0; j < 4; ++j)
            if (gy == srcY && gx0 + j == srcX) { srcI = i; srcJ = j; }
        ownRow[i] = ((unsigned)(rb + i - 16) < 8u);   // own local y [16,24)
        rec[i] = ownedCol && ownRow[i] && (gy == recY);
    }

    float injs[K];
    #pragma unroll
    for (int k = 0; k < K; ++k)
        injs[k] = (srcI >= 0) ? params[4 + t0 + k] : 0.0f;

    __syncthreads();

    int p = 0;
    #pragma unroll
    for (int k = 0; k < K; ++k) {
        const float* cur = lds[p];
        float* nxt = lds[p ^ 1];
        // center column quads, rows rb-4 .. rb+5
        f32x4 win[10];
        #pragma unroll
        for (int m = 0; m < 10; ++m)
            win[m] = *(const f32x4*)&cur[(rb - 4 + m) * TSTR + x4];
        #pragma unroll
        for (int i = 0; i < 2; ++i) {
            const int y = rb + i;
            const f32x4 lq = *(const f32x4*)&cur[y * TSTR + x4 - 4];
            const f32x4 rq = *(const f32x4*)&cur[y * TSTR + x4 + 4];
            float h[12];
            #pragma unroll
            for (int j = 0; j < 4; ++j) {
                h[j] = lq[j]; h[4 + j] = win[4 + i][j]; h[8 + j] = rq[j];
            }
            f32x4 nv;
            #pragma unroll
            for (int j = 0; j < 4; ++j) {
                const float ctr = h[4 + j];
                const float lap = 2.0f * C0f * ctr
                  + C1f * (win[3 + i][j] + win[5 + i][j] + h[3 + j] + h[5 + j])
                  + C2f * (win[2 + i][j] + win[6 + i][j] + h[2 + j] + h[6 + j])
                  + C3f * (win[1 + i][j] + win[7 + i][j] + h[1 + j] + h[7 + j])
                  + C4f * (win[0 + i][j] + win[8 + i][j] + h[0 + j] + h[8 + j]);
                float nvj = 2.0f * ctr - prevq[i][j] + scq[i][j] * lap;
                if (srcI == i && srcJ == j) nvj += injs[k];
                nv[j] = nvj;
                prevq[i][j] = ctr;
            }
            *(f32x4*)&nxt[y * TSTR + x4] = nv;
            valq[i] = nv;
            if (rec[i])
                *(f32x4*)&out[(size_t)(t0 + k) * NXg + (gx0 - 4)] = nv;
        }
        if (k < K - 1) __syncthreads();
        p ^= 1;
    }

    // Write back owned 32x8 region of the last two time levels.
    if (ownedCol) {
        #pragma unroll
        for (int i = 0; i < 2; ++i) {
            if (ownRow[i]) {
                const size_t g = (size_t)gyv[i] * DIMg + gx0;
                *(f32x4*)&Pd[g] = prevq[i];   // u(t0+3)
                *(f32x4*)&Cd[g] = valq[i];    // u(t0+4)
            }
        }
    }
}

extern "C" void kernel_launch(void* const* d_in, const int* in_sizes, int n_in,
                              void* d_out, int out_size, void* d_ws, size_t ws_size,
                              hipStream_t stream) {
    const float* vel = (const float*)d_in[0];
    const float* w   = (const float*)d_in[1];
    const int*   sx  = (const int*)d_in[2];
    const int*   sy  = (const int*)d_in[3];
    const int*   ry  = (const int*)d_in[4];
    float* out = (float*)d_out;

    float* ws     = (float*)d_ws;     // needs ~5.41 MB
    float* scale  = ws;
    float* params = ws + DIMg * DIMg;
    float* fld    = params + 512;
    float* P[2]   = { fld,               fld + 2 * DIMg * DIMg };
    float* C[2]   = { fld + DIMg * DIMg, fld + 3 * DIMg * DIMg };

    time2d_init<<<(DIMg * DIMg + 255) / 256, 256, 0, stream>>>(
        vel, w, sx, sy, ry, scale, fld, params);

    dim3 grid(16, 64);   // 1024 blocks, own 32x8 each, 4 blocks/CU
    for (int c = 0; c < NCHUNK; ++c) {
        const int s = c & 1, d = s ^ 1;
        time2d_chunk<KSTEP><<<grid, 256, 0, stream>>>(P[s], C[s], P[d], C[d],
                                                      scale, params, out,
                                                      c * KSTEP);
    }
}